// Round 1
// baseline (481.326 us; speedup 1.0000x reference)
//
#include <hip/hip_runtime.h>
#include <math.h>

#define EPS 1e-7f
#define JC 24
#define MD 16
#define CHN 32
#define D_ 4
#define H_ 14
#define W_ 14
#define NI 784
#define CI 25088
#define BATCH 4
#define NP 792          // 384 sumv + 384 sumv2 + 24 den
#define ST_STRIDE 816   // 384 mean + 384 inv2s + 24 coef + 24 loga
#define IB 8
#define TWO_PI 6.28318530717958647692f

__device__ __forceinline__ float groupReduceSum16(float x) {
    x += __shfl_xor(x, 1);
    x += __shfl_xor(x, 2);
    x += __shfl_xor(x, 4);
    x += __shfl_xor(x, 8);
    return x;
}

// One thread per (j, m). 384 threads = 6 waves. Each block handles a chunk of i's
// for one batch b, recomputes votes on the fly, accumulates sum(r), sum(r*v),
// sum(r*v^2) in registers, writes one partial record.
template<int PASS>
__global__ __launch_bounds__(384)
void accum_kernel(const float* __restrict__ pose, const float* __restrict__ act,
                  const float* __restrict__ w, const float* __restrict__ ST,
                  float* __restrict__ P, int nblk) {
    __shared__ float w_lds[CHN * JC * 16];   // 48 KB
    __shared__ float u_lds[IB * 16];
    __shared__ float a_lds[IB];
    __shared__ float wmax[IB][6];
    __shared__ float wsum[IB][6];

    const int t = threadIdx.x;
    const int j = t >> 4, m = t & 15;
    const int p = m >> 2, q = m & 3;
    const int b = blockIdx.y, blk = blockIdx.x;
    const int wid = t >> 6;
    const int lane = t & 63;

    for (int idx = t; idx < CHN * JC * 16; idx += 384)
        w_lds[idx] = w[idx];

    float meanr = 0.f, inv2sr = 0.f, coefr = 0.f, logar = 0.f;
    if (PASS) {
        const float* stb = ST + b * ST_STRIDE;
        meanr  = stb[t];
        inv2sr = stb[384 + t];
        coefr  = stb[768 + j];
        logar  = stb[792 + j];
    }

    float accR = 0.f, accV = 0.f, accV2 = 0.f;

    const int i0 = (int)((long long)CI * blk / nblk);
    const int i1 = (int)((long long)CI * (blk + 1) / nblk);

    for (int g = i0; g < i1; g += IB) {
        __syncthreads();   // protect LDS reuse from previous group
        // stage pose (IB*16 floats) + activations (IB floats); zero-pad past i1
        if (t < IB * 16) {
            int ib = t >> 4;
            u_lds[t] = (g + ib < i1) ? pose[(size_t)(b * CI + g) * 16 + t] : 0.f;
        }
        if (t >= 256 && t < 256 + IB) {
            int ib = t - 256;
            float a = 0.f;
            if (g + ib < i1) {
                a = act[b * CI + g + ib];
                a = (a >= 0.f) ? a : 0.f;   // ROUTE_MIN clamp
            }
            a_lds[ib] = a;
        }
        __syncthreads();

        float v[IB];
        float le[IB];

        // Phase A: votes + expo + logits + per-wave max
        #pragma unroll
        for (int ib = 0; ib < IB; ++ib) {
            const int i = g + ib;
            const int c = i & 31;
            const int sp = i >> 5;
            const float* uu = &u_lds[ib * 16 + p * 4];
            const float* ww = &w_lds[c * 384 + j * 16 + q];
            float vv = uu[0] * ww[0] + uu[1] * ww[4] + uu[2] * ww[8] + uu[3] * ww[12];
            if (m >= 13) {
                int d = sp / (H_ * W_), rem = sp % (H_ * W_);
                int h = rem / W_, wv = rem % W_;
                vv += (m == 13) ? (float)(d - D_ / 2)
                    : (m == 14) ? (float)(h - H_ / 2)
                                : (float)(wv - W_ / 2);
            }
            v[ib] = vv;
            if (PASS) {
                float e = vv - meanr;
                e = e * e * inv2sr;
                e = groupReduceSum16(e);                 // expo_j (all 16 lanes)
                float logit = logar + coefr - e;
                le[ib] = logit;
                float wm = fmaxf(logit, __shfl_xor(logit, 16));
                wm = fmaxf(wm, __shfl_xor(wm, 32));      // max over wave's 4 j's
                if (lane == 0) wmax[ib][wid] = wm;
            }
        }

        if (PASS) {
            __syncthreads();
            // Phase B: global max, exp, per-wave sum
            #pragma unroll
            for (int ib = 0; ib < IB; ++ib) {
                float gm = wmax[ib][0];
                #pragma unroll
                for (int k2 = 1; k2 < 6; ++k2) gm = fmaxf(gm, wmax[ib][k2]);
                float e = __expf(le[ib] - gm);
                le[ib] = e;
                float s4 = e + __shfl_xor(e, 16);
                s4 += __shfl_xor(s4, 32);                // sum over wave's 4 j's
                if (lane == 0) wsum[ib][wid] = s4;
            }
            __syncthreads();
            // Phase C: softmax finish + accumulate
            #pragma unroll
            for (int ib = 0; ib < IB; ++ib) {
                float S = wsum[ib][0];
                #pragma unroll
                for (int k2 = 1; k2 < 6; ++k2) S += wsum[ib][k2];
                float r = (le[ib] / S) * a_lds[ib];
                accR  += r;
                accV  += r * v[ib];
                accV2 += r * v[ib] * v[ib];
            }
        } else {
            #pragma unroll
            for (int ib = 0; ib < IB; ++ib) {
                float r = a_lds[ib] * (1.0f / 24.0f);    // r0 = a_i / Cj
                accR  += r;
                accV  += r * v[ib];
                accV2 += r * v[ib] * v[ib];
            }
        }
    }

    float* Pp = P + (size_t)(b * nblk + blk) * NP;
    Pp[t]       = accV;
    Pp[384 + t] = accV2;
    if (m == 0) Pp[768 + j] = accR;
}

// One block per batch. Reduces partials, computes mean/s/cost/cm/cs/a_j,
// writes E-step stats; final instance also writes d_out.
__global__ __launch_bounds__(384)
void stats_kernel(const float* __restrict__ P, const float* __restrict__ beta_v,
                  const float* __restrict__ beta_a, float* __restrict__ ST,
                  float* __restrict__ out, int nblk, float it, int final_) {
    __shared__ float red[8];
    const int t = threadIdx.x;
    const int j = t >> 4, m = t & 15;
    const int b = blockIdx.x;
    const int wid = t >> 6, lane = t & 63;

    float S1 = 0.f, S2 = 0.f, R = 0.f;
    for (int blk = 0; blk < nblk; ++blk) {
        const float* Pp = P + (size_t)(b * nblk + blk) * NP;
        S1 += Pp[t];
        S2 += Pp[384 + t];
        R  += Pp[768 + j];
    }

    float den  = R + EPS;          // r.sum + EPS
    float denp = den + EPS;        // (den + EPS) as in reference
    float mean = S1 / denp;
    float s = (S2 - 2.f * mean * S1 + mean * mean * R) / denp;
    s = fmaxf(s, 0.f);             // guard fp rounding; reference s >= 0

    // cost_j = den * sum_m(beta_v + log(sqrt(s+EPS)+EPS))
    float c1 = beta_v[j * 16 + m] + logf(sqrtf(s + EPS) + EPS);
    float sc = groupReduceSum16(c1);
    float cost = den * sc;

    // cm = mean_j(cost)
    float t4 = cost + __shfl_xor(cost, 16);
    t4 += __shfl_xor(t4, 32);
    __syncthreads();
    if (lane == 0) red[wid] = t4;
    __syncthreads();
    float tot = red[0] + red[1] + red[2] + red[3] + red[4] + red[5];
    float cm = tot / 24.f;

    // cs = sqrt(sum_j (cost-cm)^2 / 24 + EPS)
    float d2 = cost - cm; d2 *= d2;
    float t4b = d2 + __shfl_xor(d2, 16);
    t4b += __shfl_xor(t4b, 32);
    __syncthreads();
    if (lane == 0) red[wid] = t4b;
    __syncthreads();
    float tot2 = red[0] + red[1] + red[2] + red[3] + red[4] + red[5];
    float cs = sqrtf(tot2 / 24.f + EPS);

    float x = it * (beta_a[j] + (cm - cost) / (cs + EPS));
    float aj = 1.f / (1.f + expf(-x));

    // coef = -0.5 * sum_m log(2*pi*s + EPS)
    float lg = logf(TWO_PI * s + EPS);
    float coef = -0.5f * groupReduceSum16(lg);

    float* stb = ST + b * ST_STRIDE;
    stb[t]       = mean;
    stb[384 + t] = 1.f / (2.f * s + EPS);
    if (m == 0) {
        stb[768 + j] = coef;
        stb[792 + j] = logf(aj + EPS);
    }
    if (final_) {
        out[(b * 24 + j) * 16 + m] = mean;
        if (m == 0) out[1536 + b * 24 + j] = aj;
    }
}

extern "C" void kernel_launch(void* const* d_in, const int* in_sizes, int n_in,
                              void* d_out, int out_size, void* d_ws, size_t ws_size,
                              hipStream_t stream) {
    const float* pose   = (const float*)d_in[0];
    const float* act    = (const float*)d_in[1];
    const float* w      = (const float*)d_in[2];
    const float* beta_v = (const float*)d_in[3];
    const float* beta_a = (const float*)d_in[4];
    float* out = (float*)d_out;
    float* W   = (float*)d_ws;

    int nblk = 128;
    while (nblk > 1 &&
           (size_t)(BATCH * nblk * NP + BATCH * ST_STRIDE) * 4 > ws_size)
        nblk >>= 1;

    float* P  = W;
    float* ST = W + (size_t)BATCH * nblk * NP;

    dim3 agrid(nblk, BATCH), ablock(384);
    dim3 sgrid(BATCH), sblock(384);

    accum_kernel<0><<<agrid, ablock, 0, stream>>>(pose, act, w, ST, P, nblk);
    stats_kernel<<<sgrid, sblock, 0, stream>>>(P, beta_v, beta_a, ST, out, nblk, 0.5f, 0);
    accum_kernel<1><<<agrid, ablock, 0, stream>>>(pose, act, w, ST, P, nblk);
    stats_kernel<<<sgrid, sblock, 0, stream>>>(P, beta_v, beta_a, ST, out, nblk, 0.6f, 0);
    accum_kernel<1><<<agrid, ablock, 0, stream>>>(pose, act, w, ST, P, nblk);
    stats_kernel<<<sgrid, sblock, 0, stream>>>(P, beta_v, beta_a, ST, out, nblk, 0.8f, 1);
}

// Round 2
// 217.040 us; speedup vs baseline: 2.2177x; 2.2177x over previous
//
#include <hip/hip_runtime.h>
#include <math.h>

#define EPS 1e-7f
#define JC 24
#define CHN 32
#define D_ 4
#define H_ 14
#define W_ 14
#define NI 784
#define CI 25088
#define BATCH 4
#define NP 792          // 384 sumv + 384 sumv2 + 24 sumr
#define ST_STRIDE 792   // 384 A + 384 B2 + 24 K
#define TWO_PI 6.28318530717958647692f
#define NEG_BIG -1e30f

__device__ __forceinline__ float groupReduceSum16(float x) {
    x += __shfl_xor(x, 1);
    x += __shfl_xor(x, 2);
    x += __shfl_xor(x, 4);
    x += __shfl_xor(x, 8);
    return x;
}

// thread = (sp_sub = tid>>5, jlane = tid&31). 256 threads = 8 sp x 32 j-lanes
// (24 active j). Votes fully in registers; softmax over j via intra-half-wave
// shuffles; no barriers / no LDS in the main loop. w held in 16 regs per
// c-segment (c = outer loop). One LDS tree-reduce at block end.
template<int PASS, int SPB, int CSEG>
__global__ __launch_bounds__(256, 3)
void accum_kernel(const float* __restrict__ pose, const float* __restrict__ act,
                  const float* __restrict__ w, const float* __restrict__ ST,
                  float* __restrict__ P) {
    __shared__ float red[4 * JC * 33];   // 12.7 KB

    const int t = threadIdx.x;
    const int h = t >> 5;          // 0..7 (sp within round)
    const int jl = t & 31;
    const int jc = jl < 23 ? jl : 23;
    const int b = blockIdx.z;
    const int c0 = blockIdx.y * CSEG;
    const int sp0 = blockIdx.x * SPB;

    float A[16], B2[16], K = 0.f;
    if (PASS) {
        const float* stb = ST + b * ST_STRIDE;
        #pragma unroll
        for (int m4 = 0; m4 < 4; ++m4) {
            float4 a4 = *(const float4*)&stb[jc * 16 + m4 * 4];
            A[m4*4+0] = a4.x; A[m4*4+1] = a4.y; A[m4*4+2] = a4.z; A[m4*4+3] = a4.w;
            float4 b4 = *(const float4*)&stb[384 + jc * 16 + m4 * 4];
            B2[m4*4+0] = b4.x; B2[m4*4+1] = b4.y; B2[m4*4+2] = b4.z; B2[m4*4+3] = b4.w;
        }
        K = stb[768 + jc];
    }

    float accR = 0.f, accV[16], accV2[16];
    #pragma unroll
    for (int m = 0; m < 16; ++m) { accV[m] = 0.f; accV2[m] = 0.f; }

    #pragma unroll 1
    for (int r = 0; r < SPB / 8; ++r) {
        const int sp = sp0 + r * 8 + h;
        // coordinate addition values for this spatial position
        const int dd = sp / (H_ * W_);
        const int rem = sp - dd * (H_ * W_);
        const int hh = rem / W_;
        const int ww = rem - hh * W_;
        const float cd = (float)(dd - D_ / 2);
        const float ch = (float)(hh - H_ / 2);
        const float cw = (float)(ww - W_ / 2);

        #pragma unroll 2
        for (int cs = 0; cs < CSEG; ++cs) {
            const int c = c0 + cs;
            // w[c][j][16] -> 16 regs (k-major rows of the 4x4)
            const float* wp = w + ((size_t)c * JC + jc) * 16;
            float4 w0 = *(const float4*)(wp + 0);
            float4 w1 = *(const float4*)(wp + 4);
            float4 w2 = *(const float4*)(wp + 8);
            float4 w3 = *(const float4*)(wp + 12);
            // u = pose[b][sp][c][16]
            const float* up = pose + (((size_t)b * NI + sp) * CHN + c) * 16;
            float a = act[((size_t)b * NI + sp) * CHN + c];
            a = fmaxf(a, 0.f);

            float v[16];
            #pragma unroll
            for (int p = 0; p < 4; ++p) {
                float4 u = *(const float4*)(up + p * 4);
                v[p*4+0] = u.x*w0.x + u.y*w1.x + u.z*w2.x + u.w*w3.x;
                v[p*4+1] = u.x*w0.y + u.y*w1.y + u.z*w2.y + u.w*w3.y;
                v[p*4+2] = u.x*w0.z + u.y*w1.z + u.z*w2.z + u.w*w3.z;
                v[p*4+3] = u.x*w0.w + u.y*w1.w + u.z*w2.w + u.w*w3.w;
            }
            v[13] += cd; v[14] += ch; v[15] += cw;

            float rr;
            if (PASS) {
                float expo = 0.f;
                #pragma unroll
                for (int m = 0; m < 16; ++m) {
                    float tm = fmaf(A[m], v[m], -B2[m]);
                    expo = fmaf(v[m], tm, expo);
                }
                float logit = (jl < JC) ? (K - expo) : NEG_BIG;
                float gm = logit;
                gm = fmaxf(gm, __shfl_xor(gm, 1));
                gm = fmaxf(gm, __shfl_xor(gm, 2));
                gm = fmaxf(gm, __shfl_xor(gm, 4));
                gm = fmaxf(gm, __shfl_xor(gm, 8));
                gm = fmaxf(gm, __shfl_xor(gm, 16));
                float e = __expf(logit - gm);
                float S = e;
                S += __shfl_xor(S, 1);
                S += __shfl_xor(S, 2);
                S += __shfl_xor(S, 4);
                S += __shfl_xor(S, 8);
                S += __shfl_xor(S, 16);
                rr = __fdividef(e, S) * a;
            } else {
                rr = a * (1.0f / 24.0f);
            }

            accR += rr;
            #pragma unroll
            for (int m = 0; m < 16; ++m) {
                float rv = rr * v[m];
                accV[m] += rv;
                accV2[m] = fmaf(rv, v[m], accV2[m]);
            }
        }
    }

    // fold the two half-waves (sp pairs), then LDS tree over 4 waves
    accR += __shfl_xor(accR, 32);
    #pragma unroll
    for (int m = 0; m < 16; ++m) {
        accV[m]  += __shfl_xor(accV[m], 32);
        accV2[m] += __shfl_xor(accV2[m], 32);
    }
    const int wid = t >> 6;
    if ((t & 63) < JC) {
        float* rp = &red[(wid * JC + jl) * 33];
        #pragma unroll
        for (int m = 0; m < 16; ++m) { rp[m] = accV[m]; rp[16 + m] = accV2[m]; }
        rp[32] = accR;
    }
    __syncthreads();

    const int nblkTot = gridDim.x * gridDim.y;
    const int pidx = blockIdx.y * gridDim.x + blockIdx.x;
    float* Pp = P + ((size_t)b * nblkTot + pidx) * NP;
    for (int idx = t; idx < NP; idx += 256) {
        int j, v;
        if (idx < 384)      { j = idx >> 4;        v = idx & 15; }
        else if (idx < 768) { j = (idx-384) >> 4;  v = 16 + ((idx-384) & 15); }
        else                { j = idx - 768;       v = 32; }
        int o = (j * 33) + v;
        float s = red[o] + red[792 + o] + red[2*792 + o] + red[3*792 + o];
        Pp[idx] = s;
    }
}

// One block per batch. Reduces partials, computes mean/s/cost/cm/cs/a_j,
// emits A/B2/K for the next E-step; final instance writes d_out.
__global__ __launch_bounds__(384)
void stats_kernel(const float* __restrict__ P, const float* __restrict__ beta_v,
                  const float* __restrict__ beta_a, float* __restrict__ ST,
                  float* __restrict__ out, int nblk, float it, int final_) {
    __shared__ float red[8];
    const int t = threadIdx.x;
    const int j = t >> 4, m = t & 15;
    const int b = blockIdx.x;
    const int wid = t >> 6, lane = t & 63;

    float S1 = 0.f, S2 = 0.f, R = 0.f;
    #pragma unroll 4
    for (int blk = 0; blk < nblk; ++blk) {
        const float* Pp = P + ((size_t)b * nblk + blk) * NP;
        S1 += Pp[t];
        S2 += Pp[384 + t];
        R  += Pp[768 + j];
    }

    float den  = R + EPS;
    float denp = den + EPS;
    float mean = S1 / denp;
    float s = (S2 - 2.f * mean * S1 + mean * mean * R) / denp;
    s = fmaxf(s, 0.f);

    float c1 = beta_v[j * 16 + m] + logf(sqrtf(s + EPS) + EPS);
    float sc = groupReduceSum16(c1);
    float cost = den * sc;

    float t4 = cost + __shfl_xor(cost, 16);
    t4 += __shfl_xor(t4, 32);
    __syncthreads();
    if (lane == 0) red[wid] = t4;
    __syncthreads();
    float tot = red[0] + red[1] + red[2] + red[3] + red[4] + red[5];
    float cm = tot / 24.f;

    float d2 = cost - cm; d2 *= d2;
    float t4b = d2 + __shfl_xor(d2, 16);
    t4b += __shfl_xor(t4b, 32);
    __syncthreads();
    if (lane == 0) red[wid] = t4b;
    __syncthreads();
    float tot2 = red[0] + red[1] + red[2] + red[3] + red[4] + red[5];
    float cs = sqrtf(tot2 / 24.f + EPS);

    float x = it * (beta_a[j] + (cm - cost) / (cs + EPS));
    float aj = 1.f / (1.f + expf(-x));

    float coef = -0.5f * groupReduceSum16(logf(TWO_PI * s + EPS));

    float Aq = 1.f / (2.f * s + EPS);
    float B2q = 2.f * mean * Aq;
    float Kpart = groupReduceSum16(mean * mean * Aq);
    float Kq = logf(aj + EPS) + coef + Kpart;

    float* stb = ST + b * ST_STRIDE;
    stb[t]       = Aq;
    stb[384 + t] = B2q;
    if (m == 0) stb[768 + j] = Kq;

    if (final_) {
        out[(b * 24 + j) * 16 + m] = mean;
        if (m == 0) out[1536 + b * 24 + j] = aj;
    }
}

template<int SPB, int CSEG>
static void run_all(int spblk, int cblk,
                    const float* pose, const float* act, const float* w,
                    const float* beta_v, const float* beta_a,
                    float* P, float* ST, float* out, hipStream_t stream) {
    dim3 agrid(spblk, cblk, BATCH), ablock(256);
    dim3 sgrid(BATCH), sblock(384);
    int nblk = spblk * cblk;
    accum_kernel<0, SPB, CSEG><<<agrid, ablock, 0, stream>>>(pose, act, w, ST, P);
    stats_kernel<<<sgrid, sblock, 0, stream>>>(P, beta_v, beta_a, ST, out, nblk, 0.5f, 0);
    accum_kernel<1, SPB, CSEG><<<agrid, ablock, 0, stream>>>(pose, act, w, ST, P);
    stats_kernel<<<sgrid, sblock, 0, stream>>>(P, beta_v, beta_a, ST, out, nblk, 0.6f, 0);
    accum_kernel<1, SPB, CSEG><<<agrid, ablock, 0, stream>>>(pose, act, w, ST, P);
    stats_kernel<<<sgrid, sblock, 0, stream>>>(P, beta_v, beta_a, ST, out, nblk, 0.8f, 1);
}

extern "C" void kernel_launch(void* const* d_in, const int* in_sizes, int n_in,
                              void* d_out, int out_size, void* d_ws, size_t ws_size,
                              hipStream_t stream) {
    const float* pose   = (const float*)d_in[0];
    const float* act    = (const float*)d_in[1];
    const float* w      = (const float*)d_in[2];
    const float* beta_v = (const float*)d_in[3];
    const float* beta_a = (const float*)d_in[4];
    float* out = (float*)d_out;
    float* W   = (float*)d_ws;

    // config ladder: (spblk, cblk, SPB, CSEG); need (B*spblk*cblk*NP + B*792)*4 bytes
    auto need = [](int spblk, int cblk) -> size_t {
        return ((size_t)BATCH * spblk * cblk * NP + (size_t)BATCH * ST_STRIDE) * 4;
    };

    if (need(98, 4) <= ws_size) {
        float* P = W; float* ST = W + (size_t)BATCH * 98 * 4 * NP;
        run_all<8, 8>(98, 4, pose, act, w, beta_v, beta_a, P, ST, out, stream);
    } else if (need(49, 4) <= ws_size) {
        float* P = W; float* ST = W + (size_t)BATCH * 49 * 4 * NP;
        run_all<16, 8>(49, 4, pose, act, w, beta_v, beta_a, P, ST, out, stream);
    } else if (need(49, 1) <= ws_size) {
        float* P = W; float* ST = W + (size_t)BATCH * 49 * 1 * NP;
        run_all<16, 32>(49, 1, pose, act, w, beta_v, beta_a, P, ST, out, stream);
    } else {
        float* P = W; float* ST = W + (size_t)BATCH * 7 * 1 * NP;
        run_all<112, 32>(7, 1, pose, act, w, beta_v, beta_a, P, ST, out, stream);
    }
}

// Round 3
// 147.266 us; speedup vs baseline: 3.2684x; 1.4738x over previous
//
#include <hip/hip_runtime.h>
#include <math.h>

#define EPS 1e-7f
#define JC 24
#define CHN 32
#define D_ 4
#define H_ 14
#define W_ 14
#define NI 784
#define CI 25088
#define BATCH 4
#define NP 792          // 384 sumv + 384 sumv2 + 24 sumr
#define ST_STRIDE 792   // 384 SA + 384 MS + 24 K
#define NR 28           // second-stage partial count
#define TWO_PI 6.28318530717958647692f
#define NEG_BIG -1e30f

__device__ __forceinline__ float groupReduceSum16(float x) {
    x += __shfl_xor(x, 1);
    x += __shfl_xor(x, 2);
    x += __shfl_xor(x, 4);
    x += __shfl_xor(x, 8);
    return x;
}

// thread = (sp_sub = tid>>5, jlane = tid&31). 256 threads = 8 sp x 32 j-lanes
// (24 active j). Votes fully in registers; softmax over j via intra-half-wave
// shuffles; no barriers / no LDS in the main loop. w held in 16 regs per
// c-segment (c = outer loop). One LDS tree-reduce at block end.
template<int PASS, int SPB, int CSEG>
__global__ __launch_bounds__(256, 3)
void accum_kernel(const float* __restrict__ pose, const float* __restrict__ act,
                  const float* __restrict__ w, const float* __restrict__ ST,
                  float* __restrict__ P) {
    __shared__ float red[4 * JC * 33];   // 12.7 KB

    const int t = threadIdx.x;
    const int h = t >> 5;          // 0..7 (sp within round)
    const int jl = t & 31;
    const int jc = jl < 23 ? jl : 23;
    const int b = blockIdx.z;
    const int c0 = blockIdx.y * CSEG;
    const int sp0 = blockIdx.x * SPB;

    float SA[16], MS[16], K = 0.f;
    if (PASS) {
        const float* stb = ST + b * ST_STRIDE;
        #pragma unroll
        for (int m4 = 0; m4 < 4; ++m4) {
            float4 a4 = *(const float4*)&stb[jc * 16 + m4 * 4];
            SA[m4*4+0] = a4.x; SA[m4*4+1] = a4.y; SA[m4*4+2] = a4.z; SA[m4*4+3] = a4.w;
            float4 b4 = *(const float4*)&stb[384 + jc * 16 + m4 * 4];
            MS[m4*4+0] = b4.x; MS[m4*4+1] = b4.y; MS[m4*4+2] = b4.z; MS[m4*4+3] = b4.w;
        }
        K = stb[768 + jc];
    }

    float accR = 0.f, accV[16], accV2[16];
    #pragma unroll
    for (int m = 0; m < 16; ++m) { accV[m] = 0.f; accV2[m] = 0.f; }

    #pragma unroll 1
    for (int r = 0; r < SPB / 8; ++r) {
        const int sp = sp0 + r * 8 + h;
        const int dd = sp / (H_ * W_);
        const int rem = sp - dd * (H_ * W_);
        const int hh = rem / W_;
        const int ww = rem - hh * W_;
        const float cd = (float)(dd - D_ / 2);
        const float ch = (float)(hh - H_ / 2);
        const float cw = (float)(ww - W_ / 2);

        #pragma unroll 2
        for (int cs = 0; cs < CSEG; ++cs) {
            const int c = c0 + cs;
            const float* wp = w + ((size_t)c * JC + jc) * 16;
            float4 w0 = *(const float4*)(wp + 0);
            float4 w1 = *(const float4*)(wp + 4);
            float4 w2 = *(const float4*)(wp + 8);
            float4 w3 = *(const float4*)(wp + 12);
            const float* up = pose + (((size_t)b * NI + sp) * CHN + c) * 16;
            float a = act[((size_t)b * NI + sp) * CHN + c];
            a = fmaxf(a, 0.f);

            float v[16];
            #pragma unroll
            for (int p = 0; p < 4; ++p) {
                float4 u = *(const float4*)(up + p * 4);
                v[p*4+0] = u.x*w0.x + u.y*w1.x + u.z*w2.x + u.w*w3.x;
                v[p*4+1] = u.x*w0.y + u.y*w1.y + u.z*w2.y + u.w*w3.y;
                v[p*4+2] = u.x*w0.z + u.y*w1.z + u.z*w2.z + u.w*w3.z;
                v[p*4+3] = u.x*w0.w + u.y*w1.w + u.z*w2.w + u.w*w3.w;
            }
            v[13] += cd; v[14] += ch; v[15] += cw;

            float rr;
            if (PASS) {
                float expo = 0.f;
                #pragma unroll
                for (int m = 0; m < 16; ++m) {
                    float d = fmaf(v[m], SA[m], -MS[m]);   // (v - mean)*sqrt(A)
                    expo = fmaf(d, d, expo);
                }
                float logit = (jl < JC) ? (K - expo) : NEG_BIG;
                float gm = logit;
                gm = fmaxf(gm, __shfl_xor(gm, 1));
                gm = fmaxf(gm, __shfl_xor(gm, 2));
                gm = fmaxf(gm, __shfl_xor(gm, 4));
                gm = fmaxf(gm, __shfl_xor(gm, 8));
                gm = fmaxf(gm, __shfl_xor(gm, 16));
                float e = __expf(logit - gm);
                float S = e;
                S += __shfl_xor(S, 1);
                S += __shfl_xor(S, 2);
                S += __shfl_xor(S, 4);
                S += __shfl_xor(S, 8);
                S += __shfl_xor(S, 16);
                rr = __fdividef(e, S) * a;
            } else {
                rr = a * (1.0f / 24.0f);
            }

            accR += rr;
            #pragma unroll
            for (int m = 0; m < 16; ++m) {
                float rv = rr * v[m];
                accV[m] += rv;
                accV2[m] = fmaf(rv, v[m], accV2[m]);
            }
        }
    }

    accR += __shfl_xor(accR, 32);
    #pragma unroll
    for (int m = 0; m < 16; ++m) {
        accV[m]  += __shfl_xor(accV[m], 32);
        accV2[m] += __shfl_xor(accV2[m], 32);
    }
    const int wid = t >> 6;
    if ((t & 63) < JC) {
        float* rp = &red[(wid * JC + (t & 63)) * 33];
        #pragma unroll
        for (int m = 0; m < 16; ++m) { rp[m] = accV[m]; rp[16 + m] = accV2[m]; }
        rp[32] = accR;
    }
    __syncthreads();

    const int nblkTot = gridDim.x * gridDim.y;
    const int pidx = blockIdx.y * gridDim.x + blockIdx.x;
    float* Pp = P + ((size_t)b * nblkTot + pidx) * NP;
    for (int idx = t; idx < NP; idx += 256) {
        int j, v;
        if (idx < 384)      { j = idx >> 4;        v = idx & 15; }
        else if (idx < 768) { j = (idx-384) >> 4;  v = 16 + ((idx-384) & 15); }
        else                { j = idx - 768;       v = 32; }
        int o = (j * 33) + v;
        float s = red[o] + red[792 + o] + red[2*792 + o] + red[3*792 + o];
        Pp[idx] = s;
    }
}

// Stage-1 partial reduction: P (nblk partials) -> P2[b][idx][NR] (transposed).
__global__ __launch_bounds__(256)
void reduce_kernel(const float* __restrict__ P, float* __restrict__ P2,
                   int nblk, int chunk) {
    const int b = blockIdx.y;
    const int r = blockIdx.x;           // 0..NR-1
    const int t = threadIdx.x;
    const int b0 = r * chunk;
    const int b1 = min(b0 + chunk, nblk);
    for (int idx = t; idx < NP; idx += 256) {
        float s = 0.f;
        for (int blk = b0; blk < b1; ++blk)
            s += P[((size_t)b * nblk + blk) * NP + idx];
        P2[((size_t)b * NP + idx) * NR + r] = s;
    }
}

// One block per batch. Reduces NR second-stage partials (contiguous float4
// runs), computes mean/s/cost/cm/cs/a_j, emits SA/MS/K; final writes d_out.
__global__ __launch_bounds__(384)
void stats_kernel(const float* __restrict__ P2, const float* __restrict__ beta_v,
                  const float* __restrict__ beta_a, float* __restrict__ ST,
                  float* __restrict__ out, float it, int final_) {
    __shared__ float red[8];
    const int t = threadIdx.x;
    const int j = t >> 4, m = t & 15;
    const int b = blockIdx.x;
    const int wid = t >> 6, lane = t & 63;

    const float* p2b = P2 + (size_t)b * NP * NR;
    float S1 = 0.f, S2 = 0.f, R = 0.f;
    #pragma unroll
    for (int r4 = 0; r4 < NR; r4 += 4) {
        float4 a = *(const float4*)&p2b[(size_t)t * NR + r4];
        S1 += (a.x + a.y) + (a.z + a.w);
        float4 c = *(const float4*)&p2b[(size_t)(384 + t) * NR + r4];
        S2 += (c.x + c.y) + (c.z + c.w);
        float4 d = *(const float4*)&p2b[(size_t)(768 + j) * NR + r4];
        R += (d.x + d.y) + (d.z + d.w);
    }

    float den  = R + EPS;
    float denp = den + EPS;
    float mean = S1 / denp;
    float s = (S2 - 2.f * mean * S1 + mean * mean * R) / denp;
    s = fmaxf(s, 0.f);

    float c1 = beta_v[j * 16 + m] + logf(sqrtf(s + EPS) + EPS);
    float sc = groupReduceSum16(c1);
    float cost = den * sc;

    float t4 = cost + __shfl_xor(cost, 16);
    t4 += __shfl_xor(t4, 32);
    __syncthreads();
    if (lane == 0) red[wid] = t4;
    __syncthreads();
    float tot = red[0] + red[1] + red[2] + red[3] + red[4] + red[5];
    float cm = tot / 24.f;

    float d2 = cost - cm; d2 *= d2;
    float t4b = d2 + __shfl_xor(d2, 16);
    t4b += __shfl_xor(t4b, 32);
    __syncthreads();
    if (lane == 0) red[wid] = t4b;
    __syncthreads();
    float tot2 = red[0] + red[1] + red[2] + red[3] + red[4] + red[5];
    float cs = sqrtf(tot2 / 24.f + EPS);

    float x = it * (beta_a[j] + (cm - cost) / (cs + EPS));
    float aj = 1.f / (1.f + expf(-x));

    float coef = -0.5f * groupReduceSum16(logf(TWO_PI * s + EPS));

    float Aq = 1.f / (2.f * s + EPS);
    float SAq = sqrtf(Aq);

    float* stb = ST + b * ST_STRIDE;
    stb[t]       = SAq;
    stb[384 + t] = mean * SAq;
    if (m == 0) stb[768 + j] = logf(aj + EPS) + coef;

    if (final_) {
        out[(b * 24 + j) * 16 + m] = mean;
        if (m == 0) out[1536 + b * 24 + j] = aj;
    }
}

template<int SPB, int CSEG>
static void run_all(int spblk, int cblk,
                    const float* pose, const float* act, const float* w,
                    const float* beta_v, const float* beta_a,
                    float* P, float* P2, float* ST, float* out, hipStream_t stream) {
    dim3 agrid(spblk, cblk, BATCH), ablock(256);
    dim3 rgrid(NR, BATCH), rblock(256);
    dim3 sgrid(BATCH), sblock(384);
    const int nblk = spblk * cblk;
    const int chunk = (nblk + NR - 1) / NR;

    accum_kernel<0, SPB, CSEG><<<agrid, ablock, 0, stream>>>(pose, act, w, ST, P);
    reduce_kernel<<<rgrid, rblock, 0, stream>>>(P, P2, nblk, chunk);
    stats_kernel<<<sgrid, sblock, 0, stream>>>(P2, beta_v, beta_a, ST, out, 0.5f, 0);

    accum_kernel<1, SPB, CSEG><<<agrid, ablock, 0, stream>>>(pose, act, w, ST, P);
    reduce_kernel<<<rgrid, rblock, 0, stream>>>(P, P2, nblk, chunk);
    stats_kernel<<<sgrid, sblock, 0, stream>>>(P2, beta_v, beta_a, ST, out, 0.6f, 0);

    accum_kernel<1, SPB, CSEG><<<agrid, ablock, 0, stream>>>(pose, act, w, ST, P);
    reduce_kernel<<<rgrid, rblock, 0, stream>>>(P, P2, nblk, chunk);
    stats_kernel<<<sgrid, sblock, 0, stream>>>(P2, beta_v, beta_a, ST, out, 0.8f, 1);
}

extern "C" void kernel_launch(void* const* d_in, const int* in_sizes, int n_in,
                              void* d_out, int out_size, void* d_ws, size_t ws_size,
                              hipStream_t stream) {
    const float* pose   = (const float*)d_in[0];
    const float* act    = (const float*)d_in[1];
    const float* w      = (const float*)d_in[2];
    const float* beta_v = (const float*)d_in[3];
    const float* beta_a = (const float*)d_in[4];
    float* out = (float*)d_out;
    float* W   = (float*)d_ws;

    const size_t p2_elems = (size_t)BATCH * NP * NR;
    const size_t st_elems = (size_t)BATCH * ST_STRIDE;
    auto need = [&](int spblk, int cblk) -> size_t {
        return ((size_t)BATCH * spblk * cblk * NP + p2_elems + st_elems) * 4;
    };

    if (need(98, 4) <= ws_size) {
        float* P  = W;
        float* P2 = W + (size_t)BATCH * 98 * 4 * NP;
        float* ST = P2 + p2_elems;
        run_all<8, 8>(98, 4, pose, act, w, beta_v, beta_a, P, P2, ST, out, stream);
    } else if (need(49, 4) <= ws_size) {
        float* P  = W;
        float* P2 = W + (size_t)BATCH * 49 * 4 * NP;
        float* ST = P2 + p2_elems;
        run_all<16, 8>(49, 4, pose, act, w, beta_v, beta_a, P, P2, ST, out, stream);
    } else if (need(49, 1) <= ws_size) {
        float* P  = W;
        float* P2 = W + (size_t)BATCH * 49 * 1 * NP;
        float* ST = P2 + p2_elems;
        run_all<16, 32>(49, 1, pose, act, w, beta_v, beta_a, P, P2, ST, out, stream);
    } else {
        float* P  = W;
        float* P2 = W + (size_t)BATCH * 7 * 1 * NP;
        float* ST = P2 + p2_elems;
        run_all<112, 32>(7, 1, pose, act, w, beta_v, beta_a, P, P2, ST, out, stream);
    }
}

// Round 4
// 134.034 us; speedup vs baseline: 3.5911x; 1.0987x over previous
//
#include <hip/hip_runtime.h>
#include <math.h>

#define EPS 1e-7f
#define JC 24
#define CHN 32
#define D_ 4
#define H_ 14
#define W_ 14
#define NI 784
#define CI 25088
#define BATCH 4
#define NP 792          // 384 sumv + 384 sumv2 + 24 sumr
#define ST_STRIDE 792   // 384 SA + 384 MS + 24 K
#define NR 28           // second-stage partial count
#define TWO_PI 6.28318530717958647692f
#define LOG2E 1.44269504088896340736f

__device__ __forceinline__ float groupReduceSum16(float x) {
    x += __shfl_xor(x, 1);
    x += __shfl_xor(x, 2);
    x += __shfl_xor(x, 4);
    x += __shfl_xor(x, 8);
    return x;
}

// DPP lane-permute (VALU-latency, no LDS pipe).
template<int CTRL>
__device__ __forceinline__ float dpp_mv(float x) {
    return __int_as_float(__builtin_amdgcn_update_dpp(
        0, __float_as_int(x), CTRL, 0xF, 0xF, true));
}

// Sum over each 32-lane group (valid because steps 1-2 make quads uniform,
// then half_mirror acts as xor4, mirror as xor8, final shuffle folds rows).
__device__ __forceinline__ float groupSum32_dpp(float x) {
    x += dpp_mv<0xB1>(x);    // quad_perm [1,0,3,2]  : xor1
    x += dpp_mv<0x4E>(x);    // quad_perm [2,3,0,1]  : xor2
    x += dpp_mv<0x141>(x);   // row_half_mirror      : xor4-equiv
    x += dpp_mv<0x140>(x);   // row_mirror           : xor8-equiv
    x += __shfl_xor(x, 16);  // fold the two 16-rows
    return x;
}

// thread = (sp_sub = tid>>5, jlane = tid&31). 256 threads = 8 sp x 32 j-lanes
// (24 active j). Votes fully in registers; softmax over j has NO max pass
// (logits bounded above by K, only underflow possible -> S+1e-30 guard);
// denominator via DPP butterfly + one xor16 shuffle. w held in 16 regs per
// c-segment (c = outer loop). One LDS tree-reduce at block end.
template<int PASS, int SPB, int CSEG>
__global__ __launch_bounds__(256, 3)
void accum_kernel(const float* __restrict__ pose, const float* __restrict__ act,
                  const float* __restrict__ w, const float* __restrict__ ST,
                  float* __restrict__ P) {
    __shared__ float red[4 * JC * 33];   // 12.7 KB

    const int t = threadIdx.x;
    const int h = t >> 5;          // 0..7 (sp within round)
    const int jl = t & 31;
    const int jc = jl < 23 ? jl : 23;
    const int b = blockIdx.z;
    const int c0 = blockIdx.y * CSEG;
    const int sp0 = blockIdx.x * SPB;

    float SA[16], MS[16], K = 0.f;
    if (PASS) {
        const float* stb = ST + b * ST_STRIDE;
        #pragma unroll
        for (int m4 = 0; m4 < 4; ++m4) {
            float4 a4 = *(const float4*)&stb[jc * 16 + m4 * 4];
            SA[m4*4+0] = a4.x; SA[m4*4+1] = a4.y; SA[m4*4+2] = a4.z; SA[m4*4+3] = a4.w;
            float4 b4 = *(const float4*)&stb[384 + jc * 16 + m4 * 4];
            MS[m4*4+0] = b4.x; MS[m4*4+1] = b4.y; MS[m4*4+2] = b4.z; MS[m4*4+3] = b4.w;
        }
        K = stb[768 + jc];
    }

    float accR = 0.f, accV[16], accV2[16];
    #pragma unroll
    for (int m = 0; m < 16; ++m) { accV[m] = 0.f; accV2[m] = 0.f; }

    #pragma unroll 1
    for (int r = 0; r < SPB / 8; ++r) {
        const int sp = sp0 + r * 8 + h;
        const int dd = sp / (H_ * W_);
        const int rem = sp - dd * (H_ * W_);
        const int hh = rem / W_;
        const int ww = rem - hh * W_;
        const float cd = (float)(dd - D_ / 2);
        const float ch = (float)(hh - H_ / 2);
        const float cw = (float)(ww - W_ / 2);

        #pragma unroll 2
        for (int cs = 0; cs < CSEG; ++cs) {
            const int c = c0 + cs;
            const float* wp = w + ((size_t)c * JC + jc) * 16;
            float4 w0 = *(const float4*)(wp + 0);
            float4 w1 = *(const float4*)(wp + 4);
            float4 w2 = *(const float4*)(wp + 8);
            float4 w3 = *(const float4*)(wp + 12);
            const float* up = pose + (((size_t)b * NI + sp) * CHN + c) * 16;
            float a = act[((size_t)b * NI + sp) * CHN + c];
            a = fmaxf(a, 0.f);

            float v[16];
            #pragma unroll
            for (int p = 0; p < 4; ++p) {
                float4 u = *(const float4*)(up + p * 4);
                v[p*4+0] = u.x*w0.x + u.y*w1.x + u.z*w2.x + u.w*w3.x;
                v[p*4+1] = u.x*w0.y + u.y*w1.y + u.z*w2.y + u.w*w3.y;
                v[p*4+2] = u.x*w0.z + u.y*w1.z + u.z*w2.z + u.w*w3.z;
                v[p*4+3] = u.x*w0.w + u.y*w1.w + u.z*w2.w + u.w*w3.w;
            }
            v[13] += cd; v[14] += ch; v[15] += cw;

            float rr;
            if (PASS) {
                float expo = 0.f;
                #pragma unroll
                for (int m = 0; m < 16; ++m) {
                    float d = fmaf(v[m], SA[m], -MS[m]);   // (v-mean)*sqrt(A*log2e)
                    expo = fmaf(d, d, expo);
                }
                // logit in log2 units; bounded above by K (expo >= 0)
                float e = (jl < JC) ? exp2f(K - expo) : 0.f;
                float S = groupSum32_dpp(e) + 1e-30f;
                rr = e * a * __frcp_rn(S);
            } else {
                rr = a * (1.0f / 24.0f);
            }

            accR += rr;
            #pragma unroll
            for (int m = 0; m < 16; ++m) {
                float rv = rr * v[m];
                accV[m] = fmaf(rr, v[m], accV[m]);
                accV2[m] = fmaf(rv, v[m], accV2[m]);
            }
        }
    }

    accR += __shfl_xor(accR, 32);
    #pragma unroll
    for (int m = 0; m < 16; ++m) {
        accV[m]  += __shfl_xor(accV[m], 32);
        accV2[m] += __shfl_xor(accV2[m], 32);
    }
    const int wid = t >> 6;
    if ((t & 63) < JC) {
        float* rp = &red[(wid * JC + (t & 63)) * 33];
        #pragma unroll
        for (int m = 0; m < 16; ++m) { rp[m] = accV[m]; rp[16 + m] = accV2[m]; }
        rp[32] = accR;
    }
    __syncthreads();

    const int nblkTot = gridDim.x * gridDim.y;
    const int pidx = blockIdx.y * gridDim.x + blockIdx.x;
    float* Pp = P + ((size_t)b * nblkTot + pidx) * NP;
    for (int idx = t; idx < NP; idx += 256) {
        int j, v;
        if (idx < 384)      { j = idx >> 4;        v = idx & 15; }
        else if (idx < 768) { j = (idx-384) >> 4;  v = 16 + ((idx-384) & 15); }
        else                { j = idx - 768;       v = 32; }
        int o = (j * 33) + v;
        float s = red[o] + red[792 + o] + red[2*792 + o] + red[3*792 + o];
        Pp[idx] = s;
    }
}

// Stage-1 partial reduction: P (nblk partials) -> P2[b][idx][NR] (transposed).
__global__ __launch_bounds__(256)
void reduce_kernel(const float* __restrict__ P, float* __restrict__ P2,
                   int nblk, int chunk) {
    const int b = blockIdx.y;
    const int r = blockIdx.x;           // 0..NR-1
    const int t = threadIdx.x;
    const int b0 = r * chunk;
    const int b1 = min(b0 + chunk, nblk);
    for (int idx = t; idx < NP; idx += 256) {
        float s = 0.f;
        for (int blk = b0; blk < b1; ++blk)
            s += P[((size_t)b * nblk + blk) * NP + idx];
        P2[((size_t)b * NP + idx) * NR + r] = s;
    }
}

// One block per batch. Reduces NR second-stage partials (contiguous float4
// runs), computes mean/s/cost/cm/cs/a_j, emits exp2-folded SA/MS/K;
// final instance writes d_out.
__global__ __launch_bounds__(384)
void stats_kernel(const float* __restrict__ P2, const float* __restrict__ beta_v,
                  const float* __restrict__ beta_a, float* __restrict__ ST,
                  float* __restrict__ out, float it, int final_) {
    __shared__ float red[8];
    const int t = threadIdx.x;
    const int j = t >> 4, m = t & 15;
    const int b = blockIdx.x;
    const int wid = t >> 6, lane = t & 63;

    const float* p2b = P2 + (size_t)b * NP * NR;
    float S1 = 0.f, S2 = 0.f, R = 0.f;
    #pragma unroll
    for (int r4 = 0; r4 < NR; r4 += 4) {
        float4 a = *(const float4*)&p2b[(size_t)t * NR + r4];
        S1 += (a.x + a.y) + (a.z + a.w);
        float4 c = *(const float4*)&p2b[(size_t)(384 + t) * NR + r4];
        S2 += (c.x + c.y) + (c.z + c.w);
        float4 d = *(const float4*)&p2b[(size_t)(768 + j) * NR + r4];
        R += (d.x + d.y) + (d.z + d.w);
    }

    float den  = R + EPS;
    float denp = den + EPS;
    float mean = S1 / denp;
    float s = (S2 - 2.f * mean * S1 + mean * mean * R) / denp;
    s = fmaxf(s, 0.f);

    float c1 = beta_v[j * 16 + m] + logf(sqrtf(s + EPS) + EPS);
    float sc = groupReduceSum16(c1);
    float cost = den * sc;

    float t4 = cost + __shfl_xor(cost, 16);
    t4 += __shfl_xor(t4, 32);
    __syncthreads();
    if (lane == 0) red[wid] = t4;
    __syncthreads();
    float tot = red[0] + red[1] + red[2] + red[3] + red[4] + red[5];
    float cm = tot / 24.f;

    float d2 = cost - cm; d2 *= d2;
    float t4b = d2 + __shfl_xor(d2, 16);
    t4b += __shfl_xor(t4b, 32);
    __syncthreads();
    if (lane == 0) red[wid] = t4b;
    __syncthreads();
    float tot2 = red[0] + red[1] + red[2] + red[3] + red[4] + red[5];
    float cs = sqrtf(tot2 / 24.f + EPS);

    float x = it * (beta_a[j] + (cm - cost) / (cs + EPS));
    float aj = 1.f / (1.f + expf(-x));

    float coef = -0.5f * groupReduceSum16(logf(TWO_PI * s + EPS));

    float Aq = LOG2E / (2.f * s + EPS);
    float SAq = sqrtf(Aq);

    float* stb = ST + b * ST_STRIDE;
    stb[t]       = SAq;
    stb[384 + t] = mean * SAq;
    if (m == 0) stb[768 + j] = (logf(aj + EPS) + coef) * LOG2E;

    if (final_) {
        out[(b * 24 + j) * 16 + m] = mean;
        if (m == 0) out[1536 + b * 24 + j] = aj;
    }
}

template<int SPB, int CSEG>
static void run_all(int spblk, int cblk,
                    const float* pose, const float* act, const float* w,
                    const float* beta_v, const float* beta_a,
                    float* P, float* P2, float* ST, float* out, hipStream_t stream) {
    dim3 agrid(spblk, cblk, BATCH), ablock(256);
    dim3 rgrid(NR, BATCH), rblock(256);
    dim3 sgrid(BATCH), sblock(384);
    const int nblk = spblk * cblk;
    const int chunk = (nblk + NR - 1) / NR;

    accum_kernel<0, SPB, CSEG><<<agrid, ablock, 0, stream>>>(pose, act, w, ST, P);
    reduce_kernel<<<rgrid, rblock, 0, stream>>>(P, P2, nblk, chunk);
    stats_kernel<<<sgrid, sblock, 0, stream>>>(P2, beta_v, beta_a, ST, out, 0.5f, 0);

    accum_kernel<1, SPB, CSEG><<<agrid, ablock, 0, stream>>>(pose, act, w, ST, P);
    reduce_kernel<<<rgrid, rblock, 0, stream>>>(P, P2, nblk, chunk);
    stats_kernel<<<sgrid, sblock, 0, stream>>>(P2, beta_v, beta_a, ST, out, 0.6f, 0);

    accum_kernel<1, SPB, CSEG><<<agrid, ablock, 0, stream>>>(pose, act, w, ST, P);
    reduce_kernel<<<rgrid, rblock, 0, stream>>>(P, P2, nblk, chunk);
    stats_kernel<<<sgrid, sblock, 0, stream>>>(P2, beta_v, beta_a, ST, out, 0.8f, 1);
}

extern "C" void kernel_launch(void* const* d_in, const int* in_sizes, int n_in,
                              void* d_out, int out_size, void* d_ws, size_t ws_size,
                              hipStream_t stream) {
    const float* pose   = (const float*)d_in[0];
    const float* act    = (const float*)d_in[1];
    const float* w      = (const float*)d_in[2];
    const float* beta_v = (const float*)d_in[3];
    const float* beta_a = (const float*)d_in[4];
    float* out = (float*)d_out;
    float* W   = (float*)d_ws;

    const size_t p2_elems = (size_t)BATCH * NP * NR;
    const size_t st_elems = (size_t)BATCH * ST_STRIDE;
    auto need = [&](int spblk, int cblk) -> size_t {
        return ((size_t)BATCH * spblk * cblk * NP + p2_elems + st_elems) * 4;
    };

    if (need(98, 4) <= ws_size) {
        float* P  = W;
        float* P2 = W + (size_t)BATCH * 98 * 4 * NP;
        float* ST = P2 + p2_elems;
        run_all<8, 8>(98, 4, pose, act, w, beta_v, beta_a, P, P2, ST, out, stream);
    } else if (need(49, 4) <= ws_size) {
        float* P  = W;
        float* P2 = W + (size_t)BATCH * 49 * 4 * NP;
        float* ST = P2 + p2_elems;
        run_all<16, 8>(49, 4, pose, act, w, beta_v, beta_a, P, P2, ST, out, stream);
    } else if (need(49, 1) <= ws_size) {
        float* P  = W;
        float* P2 = W + (size_t)BATCH * 49 * 1 * NP;
        float* ST = P2 + p2_elems;
        run_all<16, 32>(49, 1, pose, act, w, beta_v, beta_a, P, P2, ST, out, stream);
    } else {
        float* P  = W;
        float* P2 = W + (size_t)BATCH * 7 * 1 * NP;
        float* ST = P2 + p2_elems;
        run_all<112, 32>(7, 1, pose, act, w, beta_v, beta_a, P, P2, ST, out, stream);
    }
}

// Round 5
// 120.663 us; speedup vs baseline: 3.9890x; 1.1108x over previous
//
#include <hip/hip_runtime.h>
#include <math.h>

#define EPS 1e-7f
#define JC 24
#define CHN 32
#define D_ 4
#define H_ 14
#define W_ 14
#define NI 784
#define CI 25088
#define BATCH 4
#define NP 792          // 384 sumv + 384 sumv2 + 24 sumr
#define ST_STRIDE 792   // 384 SA + 384 MS + 24 K
#define NR 28           // second-stage partial count
#define TWO_PI 6.28318530717958647692f
#define LOG2E 1.44269504088896340736f

__device__ __forceinline__ float groupReduceSum16(float x) {
    x += __shfl_xor(x, 1);
    x += __shfl_xor(x, 2);
    x += __shfl_xor(x, 4);
    x += __shfl_xor(x, 8);
    return x;
}

// DPP lane-permute (VALU-latency, no LDS pipe).
template<int CTRL>
__device__ __forceinline__ float dpp_mv(float x) {
    return __int_as_float(__builtin_amdgcn_update_dpp(
        0, __float_as_int(x), CTRL, 0xF, 0xF, true));
}

// Sum over each 32-lane group (steps 1-2 make quads uniform, so half/row
// mirror act as xor4/xor8; final shuffle folds the two 16-rows).
__device__ __forceinline__ float groupSum32_dpp(float x) {
    x += dpp_mv<0xB1>(x);    // quad_perm [1,0,3,2]  : xor1
    x += dpp_mv<0x4E>(x);    // quad_perm [2,3,0,1]  : xor2
    x += dpp_mv<0x141>(x);   // row_half_mirror      : xor4-equiv
    x += dpp_mv<0x140>(x);   // row_mirror           : xor8-equiv
    x += __shfl_xor(x, 16);  // fold the two 16-rows
    return x;
}

// thread = (sp_sub = tid>>5, jlane = tid&31). 256 threads = 8 sp x 32 j-lanes
// (24 active j). Votes fully in registers; softmax over j has NO max pass
// (logits bounded above by K, only underflow possible -> S+1e-30 guard);
// denominator via DPP butterfly + one xor16 shuffle. Inner c-loop is
// software-pipelined: next iteration's u/w/act loads issue before the
// current vote/softmax chain. One LDS tree-reduce at block end.
template<int PASS, int SPB, int CSEG>
__global__ __launch_bounds__(256, 3)
void accum_kernel(const float* __restrict__ pose, const float* __restrict__ act,
                  const float* __restrict__ w, const float* __restrict__ ST,
                  float* __restrict__ P) {
    __shared__ float red[4 * JC * 33];   // 12.7 KB

    const int t = threadIdx.x;
    const int h = t >> 5;          // 0..7 (sp within round)
    const int jl = t & 31;
    const int jc = jl < 23 ? jl : 23;
    const int b = blockIdx.z;
    const int c0 = blockIdx.y * CSEG;
    const int sp0 = blockIdx.x * SPB;

    float SA[16], MS[16], K = 0.f;
    if (PASS) {
        const float* stb = ST + b * ST_STRIDE;
        #pragma unroll
        for (int m4 = 0; m4 < 4; ++m4) {
            float4 a4 = *(const float4*)&stb[jc * 16 + m4 * 4];
            SA[m4*4+0] = a4.x; SA[m4*4+1] = a4.y; SA[m4*4+2] = a4.z; SA[m4*4+3] = a4.w;
            float4 b4 = *(const float4*)&stb[384 + jc * 16 + m4 * 4];
            MS[m4*4+0] = b4.x; MS[m4*4+1] = b4.y; MS[m4*4+2] = b4.z; MS[m4*4+3] = b4.w;
        }
        K = stb[768 + jc];
    }

    float accR = 0.f, accV[16], accV2[16];
    #pragma unroll
    for (int m = 0; m < 16; ++m) { accV[m] = 0.f; accV2[m] = 0.f; }

    #pragma unroll 1
    for (int r = 0; r < SPB / 8; ++r) {
        const int sp = sp0 + r * 8 + h;
        const int dd = sp / (H_ * W_);
        const int rem = sp - dd * (H_ * W_);
        const int hh = rem / W_;
        const int ww = rem - hh * W_;
        const float cd = (float)(dd - D_ / 2);
        const float ch = (float)(hh - H_ / 2);
        const float cw = (float)(ww - W_ / 2);

        const float* upb = pose + (((size_t)b * NI + sp) * CHN + c0) * 16;
        const float* apb = act + ((size_t)b * NI + sp) * CHN + c0;
        const float* wpb = w + ((size_t)c0 * JC + jc) * 16;

        // prefetch cs = 0
        float4 pu0 = *(const float4*)(upb + 0);
        float4 pu1 = *(const float4*)(upb + 4);
        float4 pu2 = *(const float4*)(upb + 8);
        float4 pu3 = *(const float4*)(upb + 12);
        float4 pw0 = *(const float4*)(wpb + 0);
        float4 pw1 = *(const float4*)(wpb + 4);
        float4 pw2 = *(const float4*)(wpb + 8);
        float4 pw3 = *(const float4*)(wpb + 12);
        float pa = apb[0];

        #pragma unroll 2
        for (int cs = 0; cs < CSEG; ++cs) {
            float4 uu[4] = { pu0, pu1, pu2, pu3 };
            float4 wv0 = pw0, wv1 = pw1, wv2 = pw2, wv3 = pw3;
            float a = fmaxf(pa, 0.f);

            // issue next iteration's loads now (branchless; last iter reloads)
            {
                const int nc = (cs + 1 < CSEG) ? cs + 1 : CSEG - 1;
                const float* upn = upb + nc * 16;
                const float* wpn = wpb + (size_t)nc * (JC * 16);
                pu0 = *(const float4*)(upn + 0);
                pu1 = *(const float4*)(upn + 4);
                pu2 = *(const float4*)(upn + 8);
                pu3 = *(const float4*)(upn + 12);
                pw0 = *(const float4*)(wpn + 0);
                pw1 = *(const float4*)(wpn + 4);
                pw2 = *(const float4*)(wpn + 8);
                pw3 = *(const float4*)(wpn + 12);
                pa = apb[nc];
            }

            float v[16];
            #pragma unroll
            for (int p = 0; p < 4; ++p) {
                float4 u = uu[p];
                v[p*4+0] = u.x*wv0.x + u.y*wv1.x + u.z*wv2.x + u.w*wv3.x;
                v[p*4+1] = u.x*wv0.y + u.y*wv1.y + u.z*wv2.y + u.w*wv3.y;
                v[p*4+2] = u.x*wv0.z + u.y*wv1.z + u.z*wv2.z + u.w*wv3.z;
                v[p*4+3] = u.x*wv0.w + u.y*wv1.w + u.z*wv2.w + u.w*wv3.w;
            }
            v[13] += cd; v[14] += ch; v[15] += cw;

            float rr;
            if (PASS) {
                float ex0 = 0.f, ex1 = 0.f, ex2 = 0.f, ex3 = 0.f;
                #pragma unroll
                for (int m4 = 0; m4 < 4; ++m4) {
                    float d0 = fmaf(v[m4*4+0], SA[m4*4+0], -MS[m4*4+0]);
                    float d1 = fmaf(v[m4*4+1], SA[m4*4+1], -MS[m4*4+1]);
                    float d2 = fmaf(v[m4*4+2], SA[m4*4+2], -MS[m4*4+2]);
                    float d3 = fmaf(v[m4*4+3], SA[m4*4+3], -MS[m4*4+3]);
                    ex0 = fmaf(d0, d0, ex0);
                    ex1 = fmaf(d1, d1, ex1);
                    ex2 = fmaf(d2, d2, ex2);
                    ex3 = fmaf(d3, d3, ex3);
                }
                float expo = (ex0 + ex1) + (ex2 + ex3);
                // logit in log2 units; bounded above by K (expo >= 0)
                float e = (jl < JC) ? exp2f(K - expo) : 0.f;
                float S = groupSum32_dpp(e) + 1e-30f;
                rr = e * a * __frcp_rn(S);
            } else {
                rr = a * (1.0f / 24.0f);
            }

            accR += rr;
            #pragma unroll
            for (int m = 0; m < 16; ++m) {
                accV[m]  = fmaf(rr, v[m], accV[m]);
                accV2[m] = fmaf(rr, v[m] * v[m], accV2[m]);
            }
        }
    }

    accR += __shfl_xor(accR, 32);
    #pragma unroll
    for (int m = 0; m < 16; ++m) {
        accV[m]  += __shfl_xor(accV[m], 32);
        accV2[m] += __shfl_xor(accV2[m], 32);
    }
    const int wid = t >> 6;
    if ((t & 63) < JC) {
        float* rp = &red[(wid * JC + (t & 63)) * 33];
        #pragma unroll
        for (int m = 0; m < 16; ++m) { rp[m] = accV[m]; rp[16 + m] = accV2[m]; }
        rp[32] = accR;
    }
    __syncthreads();

    const int nblkTot = gridDim.x * gridDim.y;
    const int pidx = blockIdx.y * gridDim.x + blockIdx.x;
    float* Pp = P + ((size_t)b * nblkTot + pidx) * NP;
    for (int idx = t; idx < NP; idx += 256) {
        int j, v;
        if (idx < 384)      { j = idx >> 4;        v = idx & 15; }
        else if (idx < 768) { j = (idx-384) >> 4;  v = 16 + ((idx-384) & 15); }
        else                { j = idx - 768;       v = 32; }
        int o = (j * 33) + v;
        float s = red[o] + red[792 + o] + red[2*792 + o] + red[3*792 + o];
        Pp[idx] = s;
    }
}

// Stage-1 partial reduction: P (nblk partials) -> P2[b][idx][NR] (transposed).
__global__ __launch_bounds__(256)
void reduce_kernel(const float* __restrict__ P, float* __restrict__ P2,
                   int nblk, int chunk) {
    const int b = blockIdx.y;
    const int r = blockIdx.x;           // 0..NR-1
    const int t = threadIdx.x;
    const int b0 = r * chunk;
    const int b1 = min(b0 + chunk, nblk);
    for (int idx = t; idx < NP; idx += 256) {
        float s = 0.f;
        for (int blk = b0; blk < b1; ++blk)
            s += P[((size_t)b * nblk + blk) * NP + idx];
        P2[((size_t)b * NP + idx) * NR + r] = s;
    }
}

// One block per batch. Reduces NR second-stage partials (contiguous float4
// runs), computes mean/s/cost/cm/cs/a_j, emits exp2-folded SA/MS/K;
// final instance writes d_out.
__global__ __launch_bounds__(384)
void stats_kernel(const float* __restrict__ P2, const float* __restrict__ beta_v,
                  const float* __restrict__ beta_a, float* __restrict__ ST,
                  float* __restrict__ out, float it, int final_) {
    __shared__ float red[8];
    const int t = threadIdx.x;
    const int j = t >> 4, m = t & 15;
    const int b = blockIdx.x;
    const int wid = t >> 6, lane = t & 63;

    const float* p2b = P2 + (size_t)b * NP * NR;
    float S1 = 0.f, S2 = 0.f, R = 0.f;
    #pragma unroll
    for (int r4 = 0; r4 < NR; r4 += 4) {
        float4 a = *(const float4*)&p2b[(size_t)t * NR + r4];
        S1 += (a.x + a.y) + (a.z + a.w);
        float4 c = *(const float4*)&p2b[(size_t)(384 + t) * NR + r4];
        S2 += (c.x + c.y) + (c.z + c.w);
        float4 d = *(const float4*)&p2b[(size_t)(768 + j) * NR + r4];
        R += (d.x + d.y) + (d.z + d.w);
    }

    float den  = R + EPS;
    float denp = den + EPS;
    float mean = S1 / denp;
    float s = (S2 - 2.f * mean * S1 + mean * mean * R) / denp;
    s = fmaxf(s, 0.f);

    float c1 = beta_v[j * 16 + m] + logf(sqrtf(s + EPS) + EPS);
    float sc = groupReduceSum16(c1);
    float cost = den * sc;

    float t4 = cost + __shfl_xor(cost, 16);
    t4 += __shfl_xor(t4, 32);
    __syncthreads();
    if (lane == 0) red[wid] = t4;
    __syncthreads();
    float tot = red[0] + red[1] + red[2] + red[3] + red[4] + red[5];
    float cm = tot / 24.f;

    float d2 = cost - cm; d2 *= d2;
    float t4b = d2 + __shfl_xor(d2, 16);
    t4b += __shfl_xor(t4b, 32);
    __syncthreads();
    if (lane == 0) red[wid] = t4b;
    __syncthreads();
    float tot2 = red[0] + red[1] + red[2] + red[3] + red[4] + red[5];
    float cs = sqrtf(tot2 / 24.f + EPS);

    float x = it * (beta_a[j] + (cm - cost) / (cs + EPS));
    float aj = 1.f / (1.f + expf(-x));

    float coef = -0.5f * groupReduceSum16(logf(TWO_PI * s + EPS));

    float Aq = LOG2E / (2.f * s + EPS);
    float SAq = sqrtf(Aq);

    float* stb = ST + b * ST_STRIDE;
    stb[t]       = SAq;
    stb[384 + t] = mean * SAq;
    if (m == 0) stb[768 + j] = (logf(aj + EPS) + coef) * LOG2E;

    if (final_) {
        out[(b * 24 + j) * 16 + m] = mean;
        if (m == 0) out[1536 + b * 24 + j] = aj;
    }
}

template<int SPB, int CSEG>
static void run_all(int spblk, int cblk,
                    const float* pose, const float* act, const float* w,
                    const float* beta_v, const float* beta_a,
                    float* P, float* P2, float* ST, float* out, hipStream_t stream) {
    dim3 agrid(spblk, cblk, BATCH), ablock(256);
    dim3 rgrid(NR, BATCH), rblock(256);
    dim3 sgrid(BATCH), sblock(384);
    const int nblk = spblk * cblk;
    const int chunk = (nblk + NR - 1) / NR;

    accum_kernel<0, SPB, CSEG><<<agrid, ablock, 0, stream>>>(pose, act, w, ST, P);
    reduce_kernel<<<rgrid, rblock, 0, stream>>>(P, P2, nblk, chunk);
    stats_kernel<<<sgrid, sblock, 0, stream>>>(P2, beta_v, beta_a, ST, out, 0.5f, 0);

    accum_kernel<1, SPB, CSEG><<<agrid, ablock, 0, stream>>>(pose, act, w, ST, P);
    reduce_kernel<<<rgrid, rblock, 0, stream>>>(P, P2, nblk, chunk);
    stats_kernel<<<sgrid, sblock, 0, stream>>>(P2, beta_v, beta_a, ST, out, 0.6f, 0);

    accum_kernel<1, SPB, CSEG><<<agrid, ablock, 0, stream>>>(pose, act, w, ST, P);
    reduce_kernel<<<rgrid, rblock, 0, stream>>>(P, P2, nblk, chunk);
    stats_kernel<<<sgrid, sblock, 0, stream>>>(P2, beta_v, beta_a, ST, out, 0.8f, 1);
}

extern "C" void kernel_launch(void* const* d_in, const int* in_sizes, int n_in,
                              void* d_out, int out_size, void* d_ws, size_t ws_size,
                              hipStream_t stream) {
    const float* pose   = (const float*)d_in[0];
    const float* act    = (const float*)d_in[1];
    const float* w      = (const float*)d_in[2];
    const float* beta_v = (const float*)d_in[3];
    const float* beta_a = (const float*)d_in[4];
    float* out = (float*)d_out;
    float* W   = (float*)d_ws;

    const size_t p2_elems = (size_t)BATCH * NP * NR;
    const size_t st_elems = (size_t)BATCH * ST_STRIDE;
    auto need = [&](int spblk, int cblk) -> size_t {
        return ((size_t)BATCH * spblk * cblk * NP + p2_elems + st_elems) * 4;
    };

    if (need(98, 2) <= ws_size) {
        float* P  = W;
        float* P2 = W + (size_t)BATCH * 98 * 2 * NP;
        float* ST = P2 + p2_elems;
        run_all<8, 16>(98, 2, pose, act, w, beta_v, beta_a, P, P2, ST, out, stream);
    } else if (need(49, 2) <= ws_size) {
        float* P  = W;
        float* P2 = W + (size_t)BATCH * 49 * 2 * NP;
        float* ST = P2 + p2_elems;
        run_all<16, 16>(49, 2, pose, act, w, beta_v, beta_a, P, P2, ST, out, stream);
    } else {
        float* P  = W;
        float* P2 = W + (size_t)BATCH * 7 * 1 * NP;
        float* ST = P2 + p2_elems;
        run_all<112, 32>(7, 1, pose, act, w, beta_v, beta_a, P, P2, ST, out, stream);
    }
}

// Round 6
// 106.401 us; speedup vs baseline: 4.5237x; 1.1340x over previous
//
#include <hip/hip_runtime.h>
#include <math.h>

#define EPS 1e-7f
#define JC 24
#define CHN 32
#define D_ 4
#define H_ 14
#define W_ 14
#define NI 784
#define CI 25088
#define BATCH 4
#define NP 792          // 384 sumv + 384 sumv2 + 24 sumr
#define ST_STRIDE 792   // 384 SA + 384 MS + 24 K
#define NR 28           // second-stage partial count
#define TWO_PI 6.28318530717958647692f
#define LOG2E 1.44269504088896340736f

__device__ __forceinline__ float groupReduceSum16(float x) {
    x += __shfl_xor(x, 1);
    x += __shfl_xor(x, 2);
    x += __shfl_xor(x, 4);
    x += __shfl_xor(x, 8);
    return x;
}

// DPP lane-permute (VALU-latency, no LDS pipe).
template<int CTRL>
__device__ __forceinline__ float dpp_mv(float x) {
    return __int_as_float(__builtin_amdgcn_update_dpp(
        0, __float_as_int(x), CTRL, 0xF, 0xF, true));
}

// Sum over each 32-lane group (steps 1-2 make quads uniform, so half/row
// mirror act as xor4/xor8; final shuffle folds the two 16-rows).
__device__ __forceinline__ float groupSum32_dpp(float x) {
    x += dpp_mv<0xB1>(x);    // quad_perm [1,0,3,2]  : xor1
    x += dpp_mv<0x4E>(x);    // quad_perm [2,3,0,1]  : xor2
    x += dpp_mv<0x141>(x);   // row_half_mirror      : xor4-equiv
    x += dpp_mv<0x140>(x);   // row_mirror           : xor8-equiv
    x += __shfl_xor(x, 16);  // fold the two 16-rows
    return x;
}

// thread = (sp_sub = tid>>5, jlane = tid&31). 256 threads = 8 sp x 32 j-lanes
// (24 active j). w staged in LDS transposed to j-fastest ([c][kq][24]) so the
// inner loop's per-lane w reads are conflict-free ds_read_b32 instead of
// 24-line VMEM gathers (TA pipe was the round-5 bottleneck). Votes fully in
// registers; softmax over j has NO max pass (logits bounded above by K);
// denominator via DPP butterfly + one xor16 shuffle. u/act loads software-
// pipelined. One LDS tree-reduce at block end.
template<int PASS, int SPB, int CSEG>
__global__ __launch_bounds__(256, 3)
void accum_kernel(const float* __restrict__ pose, const float* __restrict__ act,
                  const float* __restrict__ w, const float* __restrict__ ST,
                  float* __restrict__ P) {
    __shared__ float w_lds[CSEG * 16 * JC];   // [cs][kq][j], 24 KB @ CSEG=16
    __shared__ float red[4 * JC * 33];        // 12.7 KB

    const int t = threadIdx.x;
    const int h = t >> 5;          // 0..7 (sp within round)
    const int jl = t & 31;
    const int jc = jl < 23 ? jl : 23;
    const int b = blockIdx.z;
    const int c0 = blockIdx.y * CSEG;
    const int sp0 = blockIdx.x * SPB;

    // stage w slice transposed: w_lds[(cs*16+kq)*24 + j] = w[c0+cs][j][kq]
    for (int idx = t; idx < CSEG * 384; idx += 256) {
        const int cs = idx / 384;
        const int r2 = idx - cs * 384;
        const int jj = r2 >> 4;
        const int kq = r2 & 15;
        w_lds[(cs * 16 + kq) * JC + jj] = w[((size_t)(c0 + cs) * JC + jj) * 16 + kq];
    }

    float SA[16], MS[16], K = 0.f;
    if (PASS) {
        const float* stb = ST + b * ST_STRIDE;
        #pragma unroll
        for (int m4 = 0; m4 < 4; ++m4) {
            float4 a4 = *(const float4*)&stb[jc * 16 + m4 * 4];
            SA[m4*4+0] = a4.x; SA[m4*4+1] = a4.y; SA[m4*4+2] = a4.z; SA[m4*4+3] = a4.w;
            float4 b4 = *(const float4*)&stb[384 + jc * 16 + m4 * 4];
            MS[m4*4+0] = b4.x; MS[m4*4+1] = b4.y; MS[m4*4+2] = b4.z; MS[m4*4+3] = b4.w;
        }
        K = stb[768 + jc];
    }

    float accR = 0.f, accV[16], accV2[16];
    #pragma unroll
    for (int m = 0; m < 16; ++m) { accV[m] = 0.f; accV2[m] = 0.f; }

    __syncthreads();   // w_lds ready

    #pragma unroll 1
    for (int r = 0; r < SPB / 8; ++r) {
        const int sp = sp0 + r * 8 + h;
        const int dd = sp / (H_ * W_);
        const int rem = sp - dd * (H_ * W_);
        const int hh = rem / W_;
        const int ww = rem - hh * W_;
        const float cd = (float)(dd - D_ / 2);
        const float ch = (float)(hh - H_ / 2);
        const float cw = (float)(ww - W_ / 2);

        const float* upb = pose + (((size_t)b * NI + sp) * CHN + c0) * 16;
        const float* apb = act + ((size_t)b * NI + sp) * CHN + c0;

        // prefetch cs = 0 (u, act via VMEM; w comes from LDS inline)
        float4 pu0 = *(const float4*)(upb + 0);
        float4 pu1 = *(const float4*)(upb + 4);
        float4 pu2 = *(const float4*)(upb + 8);
        float4 pu3 = *(const float4*)(upb + 12);
        float pa = apb[0];

        #pragma unroll 2
        for (int cs = 0; cs < CSEG; ++cs) {
            float4 uu[4] = { pu0, pu1, pu2, pu3 };
            float a = fmaxf(pa, 0.f);

            // issue next iteration's u/act loads now (branchless; last reloads)
            {
                const int nc = (cs + 1 < CSEG) ? cs + 1 : CSEG - 1;
                const float* upn = upb + nc * 16;
                pu0 = *(const float4*)(upn + 0);
                pu1 = *(const float4*)(upn + 4);
                pu2 = *(const float4*)(upn + 8);
                pu3 = *(const float4*)(upn + 12);
                pa = apb[nc];
            }

            // w for this (cs, jc): 16 conflict-free ds_read_b32
            float wv[16];
            #pragma unroll
            for (int kq = 0; kq < 16; ++kq)
                wv[kq] = w_lds[(cs * 16 + kq) * JC + jc];

            float v[16];
            #pragma unroll
            for (int p = 0; p < 4; ++p) {
                const float4 u = uu[p];
                #pragma unroll
                for (int q = 0; q < 4; ++q) {
                    v[p*4+q] = fmaf(u.w, wv[12+q],
                               fmaf(u.z, wv[8+q],
                               fmaf(u.y, wv[4+q], u.x * wv[q])));
                }
            }
            v[13] += cd; v[14] += ch; v[15] += cw;

            float rr;
            if (PASS) {
                float ex0 = 0.f, ex1 = 0.f, ex2 = 0.f, ex3 = 0.f;
                #pragma unroll
                for (int m4 = 0; m4 < 4; ++m4) {
                    float d0 = fmaf(v[m4*4+0], SA[m4*4+0], -MS[m4*4+0]);
                    float d1 = fmaf(v[m4*4+1], SA[m4*4+1], -MS[m4*4+1]);
                    float d2 = fmaf(v[m4*4+2], SA[m4*4+2], -MS[m4*4+2]);
                    float d3 = fmaf(v[m4*4+3], SA[m4*4+3], -MS[m4*4+3]);
                    ex0 = fmaf(d0, d0, ex0);
                    ex1 = fmaf(d1, d1, ex1);
                    ex2 = fmaf(d2, d2, ex2);
                    ex3 = fmaf(d3, d3, ex3);
                }
                float expo = (ex0 + ex1) + (ex2 + ex3);
                // logit in log2 units; bounded above by K (expo >= 0)
                float e = (jl < JC) ? exp2f(K - expo) : 0.f;
                float S = groupSum32_dpp(e) + 1e-30f;
                rr = e * a * __frcp_rn(S);
            } else {
                rr = a * (1.0f / 24.0f);
            }

            accR += rr;
            #pragma unroll
            for (int m = 0; m < 16; ++m) {
                accV[m]  = fmaf(rr, v[m], accV[m]);
                accV2[m] = fmaf(rr, v[m] * v[m], accV2[m]);
            }
        }
    }

    accR += __shfl_xor(accR, 32);
    #pragma unroll
    for (int m = 0; m < 16; ++m) {
        accV[m]  += __shfl_xor(accV[m], 32);
        accV2[m] += __shfl_xor(accV2[m], 32);
    }
    const int wid = t >> 6;
    if ((t & 63) < JC) {
        float* rp = &red[(wid * JC + (t & 63)) * 33];
        #pragma unroll
        for (int m = 0; m < 16; ++m) { rp[m] = accV[m]; rp[16 + m] = accV2[m]; }
        rp[32] = accR;
    }
    __syncthreads();

    const int nblkTot = gridDim.x * gridDim.y;
    const int pidx = blockIdx.y * gridDim.x + blockIdx.x;
    float* Pp = P + ((size_t)b * nblkTot + pidx) * NP;
    for (int idx = t; idx < NP; idx += 256) {
        int j, v;
        if (idx < 384)      { j = idx >> 4;        v = idx & 15; }
        else if (idx < 768) { j = (idx-384) >> 4;  v = 16 + ((idx-384) & 15); }
        else                { j = idx - 768;       v = 32; }
        int o = (j * 33) + v;
        float s = red[o] + red[792 + o] + red[2*792 + o] + red[3*792 + o];
        Pp[idx] = s;
    }
}

// Stage-1 partial reduction: P (nblk partials) -> P2[b][idx][NR] (transposed).
__global__ __launch_bounds__(256)
void reduce_kernel(const float* __restrict__ P, float* __restrict__ P2,
                   int nblk, int chunk) {
    const int b = blockIdx.y;
    const int r = blockIdx.x;           // 0..NR-1
    const int t = threadIdx.x;
    const int b0 = r * chunk;
    const int b1 = min(b0 + chunk, nblk);
    for (int idx = t; idx < NP; idx += 256) {
        float s = 0.f;
        for (int blk = b0; blk < b1; ++blk)
            s += P[((size_t)b * nblk + blk) * NP + idx];
        P2[((size_t)b * NP + idx) * NR + r] = s;
    }
}

// One block per batch. Reduces NR second-stage partials (contiguous float4
// runs), computes mean/s/cost/cm/cs/a_j, emits exp2-folded SA/MS/K;
// final instance writes d_out.
__global__ __launch_bounds__(384)
void stats_kernel(const float* __restrict__ P2, const float* __restrict__ beta_v,
                  const float* __restrict__ beta_a, float* __restrict__ ST,
                  float* __restrict__ out, float it, int final_) {
    __shared__ float red[8];
    const int t = threadIdx.x;
    const int j = t >> 4, m = t & 15;
    const int b = blockIdx.x;
    const int wid = t >> 6, lane = t & 63;

    const float* p2b = P2 + (size_t)b * NP * NR;
    float S1 = 0.f, S2 = 0.f, R = 0.f;
    #pragma unroll
    for (int r4 = 0; r4 < NR; r4 += 4) {
        float4 a = *(const float4*)&p2b[(size_t)t * NR + r4];
        S1 += (a.x + a.y) + (a.z + a.w);
        float4 c = *(const float4*)&p2b[(size_t)(384 + t) * NR + r4];
        S2 += (c.x + c.y) + (c.z + c.w);
        float4 d = *(const float4*)&p2b[(size_t)(768 + j) * NR + r4];
        R += (d.x + d.y) + (d.z + d.w);
    }

    float den  = R + EPS;
    float denp = den + EPS;
    float mean = S1 / denp;
    float s = (S2 - 2.f * mean * S1 + mean * mean * R) / denp;
    s = fmaxf(s, 0.f);

    float c1 = beta_v[j * 16 + m] + logf(sqrtf(s + EPS) + EPS);
    float sc = groupReduceSum16(c1);
    float cost = den * sc;

    float t4 = cost + __shfl_xor(cost, 16);
    t4 += __shfl_xor(t4, 32);
    __syncthreads();
    if (lane == 0) red[wid] = t4;
    __syncthreads();
    float tot = red[0] + red[1] + red[2] + red[3] + red[4] + red[5];
    float cm = tot / 24.f;

    float d2 = cost - cm; d2 *= d2;
    float t4b = d2 + __shfl_xor(d2, 16);
    t4b += __shfl_xor(t4b, 32);
    __syncthreads();
    if (lane == 0) red[wid] = t4b;
    __syncthreads();
    float tot2 = red[0] + red[1] + red[2] + red[3] + red[4] + red[5];
    float cs = sqrtf(tot2 / 24.f + EPS);

    float x = it * (beta_a[j] + (cm - cost) / (cs + EPS));
    float aj = 1.f / (1.f + expf(-x));

    float coef = -0.5f * groupReduceSum16(logf(TWO_PI * s + EPS));

    float Aq = LOG2E / (2.f * s + EPS);
    float SAq = sqrtf(Aq);

    float* stb = ST + b * ST_STRIDE;
    stb[t]       = SAq;
    stb[384 + t] = mean * SAq;
    if (m == 0) stb[768 + j] = (logf(aj + EPS) + coef) * LOG2E;

    if (final_) {
        out[(b * 24 + j) * 16 + m] = mean;
        if (m == 0) out[1536 + b * 24 + j] = aj;
    }
}

template<int SPB, int CSEG>
static void run_all(int spblk, int cblk,
                    const float* pose, const float* act, const float* w,
                    const float* beta_v, const float* beta_a,
                    float* P, float* P2, float* ST, float* out, hipStream_t stream) {
    dim3 agrid(spblk, cblk, BATCH), ablock(256);
    dim3 rgrid(NR, BATCH), rblock(256);
    dim3 sgrid(BATCH), sblock(384);
    const int nblk = spblk * cblk;
    const int chunk = (nblk + NR - 1) / NR;

    accum_kernel<0, SPB, CSEG><<<agrid, ablock, 0, stream>>>(pose, act, w, ST, P);
    reduce_kernel<<<rgrid, rblock, 0, stream>>>(P, P2, nblk, chunk);
    stats_kernel<<<sgrid, sblock, 0, stream>>>(P2, beta_v, beta_a, ST, out, 0.5f, 0);

    accum_kernel<1, SPB, CSEG><<<agrid, ablock, 0, stream>>>(pose, act, w, ST, P);
    reduce_kernel<<<rgrid, rblock, 0, stream>>>(P, P2, nblk, chunk);
    stats_kernel<<<sgrid, sblock, 0, stream>>>(P2, beta_v, beta_a, ST, out, 0.6f, 0);

    accum_kernel<1, SPB, CSEG><<<agrid, ablock, 0, stream>>>(pose, act, w, ST, P);
    reduce_kernel<<<rgrid, rblock, 0, stream>>>(P, P2, nblk, chunk);
    stats_kernel<<<sgrid, sblock, 0, stream>>>(P2, beta_v, beta_a, ST, out, 0.8f, 1);
}

extern "C" void kernel_launch(void* const* d_in, const int* in_sizes, int n_in,
                              void* d_out, int out_size, void* d_ws, size_t ws_size,
                              hipStream_t stream) {
    const float* pose   = (const float*)d_in[0];
    const float* act    = (const float*)d_in[1];
    const float* w      = (const float*)d_in[2];
    const float* beta_v = (const float*)d_in[3];
    const float* beta_a = (const float*)d_in[4];
    float* out = (float*)d_out;
    float* W   = (float*)d_ws;

    const size_t p2_elems = (size_t)BATCH * NP * NR;
    const size_t st_elems = (size_t)BATCH * ST_STRIDE;
    auto need = [&](int spblk, int cblk) -> size_t {
        return ((size_t)BATCH * spblk * cblk * NP + p2_elems + st_elems) * 4;
    };

    if (need(98, 2) <= ws_size) {
        float* P  = W;
        float* P2 = W + (size_t)BATCH * 98 * 2 * NP;
        float* ST = P2 + p2_elems;
        run_all<8, 16>(98, 2, pose, act, w, beta_v, beta_a, P, P2, ST, out, stream);
    } else if (need(49, 2) <= ws_size) {
        float* P  = W;
        float* P2 = W + (size_t)BATCH * 49 * 2 * NP;
        float* ST = P2 + p2_elems;
        run_all<16, 16>(49, 2, pose, act, w, beta_v, beta_a, P, P2, ST, out, stream);
    } else {
        float* P  = W;
        float* P2 = W + (size_t)BATCH * 7 * 1 * NP;
        float* ST = P2 + p2_elems;
        run_all<112, 32>(7, 1, pose, act, w, beta_v, beta_a, P, P2, ST, out, stream);
    }
}